// Round 5
// baseline (368.612 us; speedup 1.0000x reference)
//
#include <hip/hip_runtime.h>
#include <hip/hip_bf16.h>
#include <math.h>

#define HW2 (256*256)
#define HW1 (128*128)

typedef __attribute__((ext_vector_type(8))) short short8;
typedef __attribute__((ext_vector_type(4))) float floatx4;

__device__ __forceinline__ float b2f(ushort u) {
    union { unsigned int i; float f; } v; v.i = ((unsigned int)u) << 16; return v.f;
}
__device__ __forceinline__ ushort f2b(float f) {
    __hip_bfloat16 h = __float2bfloat16(f); return *(ushort*)&h;
}

// ---------------------------------------------------------------------------
// All weight repacks in ONE dispatch. grid = (288, 7).
// role 0: wn_w1 (Cin=128) -> [cc][t][co][ci32]
// role 1..5: wn_w2, rb0..rb3 (Cin=64) -> same layout
// role 6: 1x1 weights -> bf16 row-major (w2 padded to 16 rows)
// ---------------------------------------------------------------------------
__global__ __launch_bounds__(256)
void repack_all(const float* __restrict__ wn_w1, const float* __restrict__ wn_w2,
                const float* __restrict__ rb_w,
                const float* __restrict__ dk_w1, const float* __restrict__ gk_w1,
                const float* __restrict__ dk_w2, const float* __restrict__ gk_w2,
                ushort* __restrict__ wt_wn1, ushort* __restrict__ wt_wn2,
                ushort* __restrict__ wt_rb,
                ushort* __restrict__ w1d, ushort* __restrict__ w1g,
                ushort* __restrict__ w2d, ushort* __restrict__ w2g) {
    int idx = blockIdx.x * 256 + threadIdx.x;
    int role = blockIdx.y;
    if (role == 0) {
        if (idx >= 73728) return;
        int o = idx / 1152; int rem = idx - o * 1152;
        int ci = rem / 9;   int t = rem - ci * 9;
        wt_wn1[(((size_t)(ci >> 5) * 9 + t) * 64 + o) * 32 + (ci & 31)] = f2b(wn_w1[idx]);
    } else if (role <= 5) {
        if (idx >= 36864) return;
        const float* w = (role == 1) ? wn_w2 : rb_w + (size_t)(role - 2) * 36864;
        ushort* wt     = (role == 1) ? wt_wn2 : wt_rb + (size_t)(role - 2) * 36864;
        int o = idx / 576; int rem = idx - o * 576;
        int ci = rem / 9;  int t = rem - ci * 9;
        wt[(((size_t)(ci >> 5) * 9 + t) * 64 + o) * 32 + (ci & 31)] = f2b(w[idx]);
    } else {
        if (idx >= 10240) return;
        if (idx < 4096)      w1d[idx] = f2b(dk_w1[idx]);
        else if (idx < 8192) w1g[idx - 4096] = f2b(gk_w1[idx - 4096]);
        else if (idx < 9216) { int i = idx - 8192; w2d[i] = (i >> 6) < 9 ? f2b(dk_w2[i]) : (ushort)0; }
        else                 { int i = idx - 9216; w2g[i] = (i >> 6) < 9 ? f2b(gk_w2[i]) : (ushort)0; }
    }
}

// ---------------------------------------------------------------------------
// NCHW fp32 -> border-padded channel-chunked bf16: [plane][(H+2)][(W+2)][32]
// ---------------------------------------------------------------------------
__global__ __launch_bounds__(256)
void to_chunked(const float* __restrict__ in, ushort* __restrict__ outc,
                int H, int W, int Cchunks) {
    int P = W + 2, Q = H + 2;
    int plane_px = P * Q;
    int idx = blockIdx.x * 256 + threadIdx.x;
    if (idx >= plane_px) return;
    int py = idx / P, px = idx - py * P;
    int bc = blockIdx.y;
    int b = bc / Cchunks, cc = bc - b * Cchunks;
    ushort* dst = outc + ((size_t)bc * plane_px + idx) * 32;
    if (py == 0 || py == Q - 1 || px == 0 || px == P - 1) {
        for (int c = 0; c < 32; ++c) dst[c] = 0;
        return;
    }
    int y = py - 1, x = px - 1;
    const float* src = in + ((size_t)b * (Cchunks * 32) + cc * 32) * H * W
                          + (size_t)y * W + x;
    for (int c = 0; c < 32; ++c)
        dst[c] = f2b(src[(size_t)c * H * W]);
}

// Merged depth+guide conversion (256x256): planes 0-3 depth, 4-7 guide.
__global__ __launch_bounds__(256)
void to_chunked_hi(const float* __restrict__ depth, const float* __restrict__ guide,
                   ushort* __restrict__ outc) {
    const int P = 258;
    int plane_px = P * P;
    int idx = blockIdx.x * 256 + threadIdx.x;
    if (idx >= plane_px) return;
    int py = idx / P, px = idx - py * P;
    int pl = blockIdx.y;                 // 0..7
    const float* srcb = (pl < 4) ? depth : guide;
    int bc = pl & 3;
    int b = bc >> 1, cc = bc & 1;
    ushort* dst = outc + ((size_t)pl * plane_px + idx) * 32;
    if (py == 0 || py == P - 1 || px == 0 || px == P - 1) {
        for (int c = 0; c < 32; ++c) dst[c] = 0;
        return;
    }
    int y = py - 1, x = px - 1;
    const float* src = srcb + ((size_t)b * 64 + cc * 32) * HW2 + (size_t)y * 256 + x;
    for (int c = 0; c < 32; ++c)
        dst[c] = f2b(src[(size_t)c * HW2]);
}

// ---------------------------------------------------------------------------
// Zero 1-px borders of both conv-output regions in one dispatch.
// region 0: buf256 (8 planes of 258x258), region 1: buf128 (8 planes of 130x130)
// ---------------------------------------------------------------------------
__global__ __launch_bounds__(256)
void zero_border2(ushort* __restrict__ buf256, ushort* __restrict__ buf128) {
    int region = blockIdx.y;
    int H = region ? 128 : 256;
    int P = H + 2, Q = H + 2;
    ushort* buf = region ? buf128 : buf256;
    int nb = 2 * P + 2 * H;
    int idx = blockIdx.x * 256 + threadIdx.x;
    if (idx >= nb * 8) return;
    int pl = idx / nb, r = idx - pl * nb;
    int py, px;
    if (r < P)          { py = 0;     px = r; }
    else if (r < 2 * P) { py = Q - 1; px = r - P; }
    else { int k = r - 2 * P; py = 1 + (k >> 1); px = (k & 1) ? P - 1 : 0; }
    ushort* dst = buf + ((size_t)pl * P * Q + (size_t)py * P + px) * 32;
    for (int c = 0; c < 32; ++c) dst[c] = 0;
}

// ---------------------------------------------------------------------------
// LDS-free, barrier-free implicit-GEMM conv3x3 (pad=1), Cout=64.
// ROWS = M-tiles per wave (4 for 256^2 convs, 2 for latency-bound 128^2).
// ---------------------------------------------------------------------------
template<int NCHUNK, int ROWS, bool RELU, bool HAS_SKIP, bool CONCAT2>
__global__ __launch_bounds__(256)
void conv3x3_reg(const ushort* __restrict__ inA, const ushort* __restrict__ inB,
                 const ushort* __restrict__ wt, const float* __restrict__ bias,
                 const ushort* __restrict__ skip, ushort* __restrict__ outc,
                 int H, int W) {
    const int P = W + 2;
    const size_t plane = (size_t)P * (H + 2) * 32;
    int tid = threadIdx.x;
    int wv = tid >> 6, lane = tid & 63, ml = lane & 15, q = lane >> 4;
    int x0 = blockIdx.x * 16;
    int rowsPerBlock = (blockDim.x >> 6) * ROWS;
    int yb = blockIdx.y * rowsPerBlock + wv * ROWS;
    int b = blockIdx.z;

    floatx4 acc[ROWS][4];
#pragma unroll
    for (int r = 0; r < ROWS; ++r)
#pragma unroll
        for (int n = 0; n < 4; ++n) acc[r][n] = (floatx4){0.f, 0.f, 0.f, 0.f};

    for (int cc = 0; cc < NCHUNK; ++cc) {
        const ushort* base;
        if (CONCAT2) {
            constexpr int HC = NCHUNK / 2;
            if (cc < HC) base = inA + ((size_t)(b * HC + cc)) * plane;
            else         base = inB + ((size_t)(b * HC + cc - HC)) * plane;
        } else {
            base = inA + ((size_t)(b * NCHUNK + cc)) * plane;
        }
        const ushort* wb = wt + (size_t)cc * 18432;
#pragma unroll
        for (int t = 0; t < 9; ++t) {
            int dy = t / 3, dx = t - 3 * dy;
            short8 afr[ROWS], bfr[4];
#pragma unroll
            for (int r = 0; r < ROWS; ++r)
                afr[r] = *(const short8*)&base[((size_t)(yb + r + dy) * P
                                               + (x0 + ml + dx)) * 32 + q * 8];
#pragma unroll
            for (int n = 0; n < 4; ++n)
                bfr[n] = *(const short8*)&wb[(size_t)(t * 64 + n * 16 + ml) * 32 + q * 8];
#pragma unroll
            for (int r = 0; r < ROWS; ++r)
#pragma unroll
                for (int n = 0; n < 4; ++n)
                    acc[r][n] = __builtin_amdgcn_mfma_f32_16x16x32_bf16(
                        afr[r], bfr[n], acc[r][n], 0, 0, 0);
        }
    }

#pragma unroll
    for (int r = 0; r < ROWS; ++r) {
        int y = yb + r;
#pragma unroll
        for (int n = 0; n < 4; ++n) {
            int ch = n * 16 + ml;
            int occ = ch >> 5, ocl = ch & 31;
            float bs = bias[ch];
            size_t pbase = ((size_t)(b * 2 + occ)) * plane + ((size_t)(y + 1) * P) * 32 + ocl;
#pragma unroll
            for (int e = 0; e < 4; ++e) {
                int x = x0 + q * 4 + e;
                float v = acc[r][n][e] + bs;
                if (RELU) v = fmaxf(v, 0.f);
                if (HAS_SKIP)
                    v += b2f(skip[((size_t)(b * 2 + occ)) * plane
                                  + ((size_t)(y + 1) * P + (x + 1)) * 32 + ocl]);
                outc[pbase + (size_t)(x + 1) * 32] = f2b(v);
            }
        }
    }
}

// ---------------------------------------------------------------------------
// Fused: wn3 (3x3 64->1) + dk/gk MFMA branches + softmax + blend + tanh + L1.
// Wave owns 16 pixels. GEMM1 [16px x 64h, K=64] -> ReLU -> LDS transpose ->
// GEMM2 (out^T [16j x 16px, K=64]). Softmax over j via 2 shfl_xor.
// wmap computed per-lane from bufB with wn3 weights staged in LDS.
// ---------------------------------------------------------------------------
__global__ __launch_bounds__(256)
void kernels_fuse_mfma(const ushort* __restrict__ depth_c, const ushort* __restrict__ guide_c,
                       const ushort* __restrict__ bufB,
                       const float* __restrict__ wn_w3, const float* __restrict__ wn_b3,
                       const ushort* __restrict__ w1d, const float* __restrict__ b1d,
                       const ushort* __restrict__ w2d, const float* __restrict__ b2d,
                       const ushort* __restrict__ w1g, const float* __restrict__ b1g,
                       const ushort* __restrict__ w2g, const float* __restrict__ b2g,
                       const float* __restrict__ aff, float* __restrict__ fuse_out) {
    __shared__ __align__(16) ushort hid[2][4][16 * 72];
    __shared__ float wl[576];

    int tid = threadIdx.x;
    for (int i = tid; i < 576; i += 256) wl[i] = wn_w3[i];
    __syncthreads();

    int wv = tid >> 6, lane = tid & 63, ml = lane & 15, q = lane >> 4;
    int p0 = blockIdx.x * 64 + wv * 16;
    int b = p0 >> 16, rem0 = p0 & 65535;
    const size_t plane = (size_t)258 * 258 * 32;

    int rem = rem0 + ml;
    int y = rem >> 8, x = rem & 255;
    size_t poff = ((size_t)(y + 1) * 258 + (x + 1)) * 32;

    // ---- wmap (wn3) inline: per-lane 3x3x64 dot from bufB ----
    float wm = wn_b3[0];
    for (int cc = 0; cc < 2; ++cc) {
        const ushort* basep = bufB + (size_t)(b * 2 + cc) * plane;
#pragma unroll
        for (int t = 0; t < 9; ++t) {
            int dy = t / 3, dx = t - 3 * dy;
            const ushort* pp = basep + ((size_t)(y + dy) * 258 + (x + dx)) * 32;
            for (int c = 0; c < 32; ++c)
                wm = fmaf(wl[(cc * 32 + c) * 9 + t], b2f(pp[c]), wm);
        }
    }

    float sm[2][4];
    for (int br = 0; br < 2; ++br) {
        const ushort* src = br ? guide_c : depth_c;
        const ushort* w1  = br ? w1g : w1d;
        const float*  b1  = br ? b1g : b1d;
        const ushort* w2  = br ? w2g : w2d;
        const float*  b2  = br ? b2g : b2d;
        ushort* h = hid[br][wv];

        short8 afr[2];
#pragma unroll
        for (int kc = 0; kc < 2; ++kc)
            afr[kc] = *(const short8*)&src[(size_t)(b * 2 + kc) * plane + poff + q * 8];

        floatx4 acc[4];
#pragma unroll
        for (int nt = 0; nt < 4; ++nt) acc[nt] = (floatx4){0.f, 0.f, 0.f, 0.f};
#pragma unroll
        for (int nt = 0; nt < 4; ++nt)
#pragma unroll
            for (int kc = 0; kc < 2; ++kc) {
                short8 bfr = *(const short8*)&w1[(size_t)((nt * 16 + ml) * 64 + kc * 32 + q * 8)];
                acc[nt] = __builtin_amdgcn_mfma_f32_16x16x32_bf16(afr[kc], bfr, acc[nt], 0, 0, 0);
            }

        // bias + ReLU, transpose via LDS (same-wave round-trip, no barrier)
#pragma unroll
        for (int nt = 0; nt < 4; ++nt) {
            float bs = b1[nt * 16 + ml];
#pragma unroll
            for (int e = 0; e < 4; ++e) {
                float v = acc[nt][e] + bs;
                v = fmaxf(v, 0.f);
                h[(q * 4 + e) * 72 + nt * 16 + ml] = f2b(v);
            }
        }

        floatx4 d2 = (floatx4){0.f, 0.f, 0.f, 0.f};
#pragma unroll
        for (int kc = 0; kc < 2; ++kc) {
            short8 a2 = *(const short8*)&w2[(size_t)(ml * 64 + kc * 32 + q * 8)];
            short8 hf = *(const short8*)&h[ml * 72 + kc * 32 + q * 8];
            d2 = __builtin_amdgcn_mfma_f32_16x16x32_bf16(a2, hf, d2, 0, 0, 0);
        }

        float lg[4];
#pragma unroll
        for (int e = 0; e < 4; ++e) {
            int j = q * 4 + e;
            lg[e] = (j < 9) ? (d2[e] + b2[j]) : -1e30f;
        }
        float m = fmaxf(fmaxf(lg[0], lg[1]), fmaxf(lg[2], lg[3]));
        m = fmaxf(m, __shfl_xor(m, 16));
        m = fmaxf(m, __shfl_xor(m, 32));
        float s = 0.f;
#pragma unroll
        for (int e = 0; e < 4; ++e) { lg[e] = __expf(lg[e] - m); s += lg[e]; }
        s += __shfl_xor(s, 16);
        s += __shfl_xor(s, 32);
        float inv = 1.f / s;
#pragma unroll
        for (int e = 0; e < 4; ++e) sm[br][e] = lg[e] * inv;
    }

    float inv_av = 1.f / (aff[0] + 1e-8f);
    float f[4];
    float s = 0.f;
#pragma unroll
    for (int e = 0; e < 4; ++e) {
        float v = wm * sm[0][e] + (1.f - wm) * sm[1][e];
        v = tanhf(v) * inv_av;
        f[e] = v;
        s += fabsf(v);
    }
    s += __shfl_xor(s, 16);
    s += __shfl_xor(s, 32);
    float ksum = s + 1e-4f;
    if (ksum < 1.f) ksum = 1.f;
    float invk = 1.f / ksum;
#pragma unroll
    for (int e = 0; e < 4; ++e) {
        int j = q * 4 + e;
        if (j < 9)
            fuse_out[((size_t)b * 9 + j) * HW2 + rem0 + ml] = f[e] * invk;
    }
}

// ---------------------------------------------------------------------------
// Fused bilinear-upsample + 9-tap dilated gather.
// Taps are stride-2 => parity constant => shared bilinear weights; the
// 9-tap x 2x2 composition collapses to a 4x4 coefficient stencil on r2.
// Row/col clamp at read == per-tap edge clamp (verified algebraically).
// ---------------------------------------------------------------------------
__global__ __launch_bounds__(256)
void fuse_apply_up(const float* __restrict__ fuse, const ushort* __restrict__ r2c,
                   float* __restrict__ out) {
    int p = blockIdx.x * 256 + threadIdx.x;
    int pl = blockIdx.y;
    int b = pl >> 1, cc = pl & 1;
    int y = p >> 8, x = p & 255;

    int my = y >> 1, mx = x >> 1;
    float wyA = (y & 1) ? 0.75f : 0.25f;  float wyB = 1.f - wyA;
    float wxA = (x & 1) ? 0.75f : 0.25f;  float wxB = 1.f - wxA;
    int R0y = my + ((y & 1) ? 0 : -1) - 1;
    int R0x = mx + ((x & 1) ? 0 : -1) - 1;

    const float* f = fuse + (size_t)b * 9 * HW2 + p;
    float coef[4][4];
#pragma unroll
    for (int k = 0; k < 4; ++k)
#pragma unroll
        for (int l = 0; l < 4; ++l) coef[k][l] = 0.f;

#pragma unroll
    for (int ty = 0; ty < 3; ++ty) {
        int yp = y + (ty - 1) * 2;
        if (yp < 0 || yp > 255) continue;
#pragma unroll
        for (int tx = 0; tx < 3; ++tx) {
            int xp = x + (tx - 1) * 2;
            if (xp < 0 || xp > 255) continue;
            float fv = f[(size_t)(ty * 3 + tx) * HW2];
            coef[ty][tx]         += fv * wyA * wxA;
            coef[ty][tx + 1]     += fv * wyA * wxB;
            coef[ty + 1][tx]     += fv * wyB * wxA;
            coef[ty + 1][tx + 1] += fv * wyB * wxB;
        }
    }

    const ushort* base = r2c + (size_t)pl * 130 * 130 * 32;
    float acc[32];
#pragma unroll
    for (int c = 0; c < 32; ++c) acc[c] = 0.f;
#pragma unroll
    for (int k = 0; k < 4; ++k) {
        int ry = R0y + k; ry = ry < 0 ? 0 : (ry > 127 ? 127 : ry);
#pragma unroll
        for (int l = 0; l < 4; ++l) {
            int rx = R0x + l; rx = rx < 0 ? 0 : (rx > 127 ? 127 : rx);
            float cf = coef[k][l];
            const ushort* u = base + ((size_t)(ry + 1) * 130 + (rx + 1)) * 32;
#pragma unroll
            for (int c = 0; c < 32; ++c) acc[c] = fmaf(cf, b2f(u[c]), acc[c]);
        }
    }
    float* ob = out + ((size_t)(b * 64 + cc * 32)) * HW2 + p;
#pragma unroll
    for (int c = 0; c < 32; ++c) ob[(size_t)c * HW2] = acc[c];
}

// ---------------------------------------------------------------------------
extern "C" void kernel_launch(void* const* d_in, const int* in_sizes, int n_in,
                              void* d_out, int out_size, void* d_ws, size_t ws_size,
                              hipStream_t stream) {
    const float* depth  = (const float*)d_in[0];
    const float* guide  = (const float*)d_in[1];
    const float* inputs = (const float*)d_in[2];
    const float* dk_w1  = (const float*)d_in[3];
    const float* dk_b1  = (const float*)d_in[4];
    const float* dk_w2  = (const float*)d_in[5];
    const float* dk_b2  = (const float*)d_in[6];
    const float* gk_w1  = (const float*)d_in[7];
    const float* gk_b1  = (const float*)d_in[8];
    const float* gk_w2  = (const float*)d_in[9];
    const float* gk_b2  = (const float*)d_in[10];
    const float* wn_w1  = (const float*)d_in[11];
    const float* wn_b1  = (const float*)d_in[12];
    const float* wn_w2  = (const float*)d_in[13];
    const float* wn_b2  = (const float*)d_in[14];
    const float* wn_w3  = (const float*)d_in[15];
    const float* wn_b3  = (const float*)d_in[16];
    const float* rb_w   = (const float*)d_in[17];
    const float* rb_b   = (const float*)d_in[18];
    const float* aff    = (const float*)d_in[19];
    float* out = (float*)d_out;

    // ---- workspace layout (float units) ----
    float* ws = (float*)d_ws;
    size_t off = 0;
    const size_t CH256 = 4260096;   // 4 planes * 258*258*32 ushorts / 2
    const size_t CH128 = 1081600;   // 4 planes * 130*130*32 ushorts / 2
    ushort* depth_c = (ushort*)(ws + off); off += CH256;
    ushort* guide_c = (ushort*)(ws + off); off += CH256;
    ushort* bufA    = (ushort*)(ws + off); off += CH256;
    ushort* bufB    = (ushort*)(ws + off); off += CH256;
    ushort* inp_c   = (ushort*)(ws + off); off += CH128;
    ushort* r0      = (ushort*)(ws + off); off += CH128;
    ushort* r1      = (ushort*)(ws + off); off += CH128;
    ushort* r2      = (ushort*)(ws + off); off += CH128;
    float* fuse     = ws + off; off += 1179648;
    ushort* wt_wn1  = (ushort*)(ws + off); off += 36864;
    ushort* wt_wn2  = (ushort*)(ws + off); off += 18432;
    ushort* wt_rb   = (ushort*)(ws + off); off += 73728;
    ushort* w1d_b   = (ushort*)(ws + off); off += 2048;
    ushort* w1g_b   = (ushort*)(ws + off); off += 2048;
    ushort* w2d_b   = (ushort*)(ws + off); off += 512;
    ushort* w2g_b   = (ushort*)(ws + off); off += 512;

    // ---- weight repack: 1 dispatch ----
    repack_all<<<dim3(288, 7), 256, 0, stream>>>(
        wn_w1, wn_w2, rb_w, dk_w1, gk_w1, dk_w2, gk_w2,
        wt_wn1, wt_wn2, wt_rb, w1d_b, w1g_b, w2d_b, w2g_b);

    // ---- activation layout conversion ----
    to_chunked_hi<<<dim3(261, 8), 256, 0, stream>>>(depth, guide, depth_c);
    to_chunked<<<dim3(67, 4), 256, 0, stream>>>(inputs, inp_c, 128, 128, 2);

    // ---- zero borders of conv-output buffers (bufA+bufB and r0+r1) ----
    zero_border2<<<dim3(33, 2), 256, 0, stream>>>(bufA, r0);

    // ---- weight-map trunk (wn3 folded into fuse kernel) ----
    conv3x3_reg<4, 4, true, false, true ><<<dim3(16, 16, 2), 256, 0, stream>>>(
        depth_c, guide_c, wt_wn1, wn_b1, nullptr, bufA, 256, 256);
    conv3x3_reg<2, 4, true, false, false><<<dim3(16, 16, 2), 256, 0, stream>>>(
        bufA, nullptr, wt_wn2, wn_b2, nullptr, bufB, 256, 256);

    // ---- wn3 + dk/gk branches + blend + tanh + normalize ----
    kernels_fuse_mfma<<<2048, 256, 0, stream>>>(depth_c, guide_c, bufB,
                                                wn_w3, wn_b3,
                                                w1d_b, dk_b1, w2d_b, dk_b2,
                                                w1g_b, gk_b1, w2g_b, gk_b2,
                                                aff, fuse);

    // ---- residual stack (128x128), 2 rows/wave for 2x occupancy ----
    conv3x3_reg<2, 2, true,  false, false><<<dim3(8, 16, 2), 256, 0, stream>>>(
        inp_c, nullptr, wt_rb + 0 * 36864, rb_b + 0 * 64, nullptr, r0, 128, 128);
    conv3x3_reg<2, 2, false, true,  false><<<dim3(8, 16, 2), 256, 0, stream>>>(
        r0, nullptr, wt_rb + 1 * 36864, rb_b + 1 * 64, inp_c, r1, 128, 128);
    conv3x3_reg<2, 2, true,  false, false><<<dim3(8, 16, 2), 256, 0, stream>>>(
        r1, nullptr, wt_rb + 2 * 36864, rb_b + 2 * 64, nullptr, r0, 128, 128);
    conv3x3_reg<2, 2, false, true,  false><<<dim3(8, 16, 2), 256, 0, stream>>>(
        r0, nullptr, wt_rb + 3 * 36864, rb_b + 3 * 64, r1, r2, 128, 128);

    // ---- fused upsample + 9-tap dilated gather ----
    fuse_apply_up<<<dim3(256, 4), 256, 0, stream>>>(fuse, r2, out);
}

// Round 6
// 329.446 us; speedup vs baseline: 1.1189x; 1.1189x over previous
//
#include <hip/hip_runtime.h>
#include <hip/hip_bf16.h>
#include <math.h>

#define HW2 (256*256)
#define HW1 (128*128)

typedef __attribute__((ext_vector_type(8))) short short8;
typedef __attribute__((ext_vector_type(4))) float floatx4;

__device__ __forceinline__ float b2f(ushort u) {
    union { unsigned int i; float f; } v; v.i = ((unsigned int)u) << 16; return v.f;
}
__device__ __forceinline__ ushort f2b(float f) {
    __hip_bfloat16 h = __float2bfloat16(f); return *(ushort*)&h;
}

// ---------------------------------------------------------------------------
// All weight repacks in ONE dispatch. grid = (288, 8).
// role 0: wn_w1 (Cin=128) -> [cc][t][co][ci32]
// role 1..5: wn_w2, rb0..rb3 (Cin=64) -> same layout
// role 6: 1x1 weights -> bf16 row-major (w2 padded to 16 rows)
// role 7: wn_w3 -> [18 kchunk][16 col][32 k] bf16, col0 = weights, rest 0
// ---------------------------------------------------------------------------
__global__ __launch_bounds__(256)
void repack_all(const float* __restrict__ wn_w1, const float* __restrict__ wn_w2,
                const float* __restrict__ rb_w,
                const float* __restrict__ dk_w1, const float* __restrict__ gk_w1,
                const float* __restrict__ dk_w2, const float* __restrict__ gk_w2,
                const float* __restrict__ wn_w3,
                ushort* __restrict__ wt_wn1, ushort* __restrict__ wt_wn2,
                ushort* __restrict__ wt_rb,
                ushort* __restrict__ w1d, ushort* __restrict__ w1g,
                ushort* __restrict__ w2d, ushort* __restrict__ w2g,
                ushort* __restrict__ wt3) {
    int idx = blockIdx.x * 256 + threadIdx.x;
    int role = blockIdx.y;
    if (role == 0) {
        if (idx >= 73728) return;
        int o = idx / 1152; int rem = idx - o * 1152;
        int ci = rem / 9;   int t = rem - ci * 9;
        wt_wn1[(((size_t)(ci >> 5) * 9 + t) * 64 + o) * 32 + (ci & 31)] = f2b(wn_w1[idx]);
    } else if (role <= 5) {
        if (idx >= 36864) return;
        const float* w = (role == 1) ? wn_w2 : rb_w + (size_t)(role - 2) * 36864;
        ushort* wt     = (role == 1) ? wt_wn2 : wt_rb + (size_t)(role - 2) * 36864;
        int o = idx / 576; int rem = idx - o * 576;
        int ci = rem / 9;  int t = rem - ci * 9;
        wt[(((size_t)(ci >> 5) * 9 + t) * 64 + o) * 32 + (ci & 31)] = f2b(w[idx]);
    } else if (role == 6) {
        if (idx >= 10240) return;
        if (idx < 4096)      w1d[idx] = f2b(dk_w1[idx]);
        else if (idx < 8192) w1g[idx - 4096] = f2b(gk_w1[idx - 4096]);
        else if (idx < 9216) { int i = idx - 8192; w2d[i] = (i >> 6) < 9 ? f2b(dk_w2[i]) : (ushort)0; }
        else                 { int i = idx - 9216; w2g[i] = (i >> 6) < 9 ? f2b(gk_w2[i]) : (ushort)0; }
    } else {
        if (idx >= 9216) return;
        int kc = idx / 512; int rem = idx - kc * 512;
        int n = rem >> 5, c = rem & 31;
        int cc = kc / 9, t = kc - cc * 9;
        wt3[idx] = (n == 0) ? f2b(wn_w3[(cc * 32 + c) * 9 + t]) : (ushort)0;
    }
}

// ---------------------------------------------------------------------------
// NCHW fp32 -> border-padded channel-chunked bf16: [plane][(H+2)][(W+2)][32]
// ---------------------------------------------------------------------------
__global__ __launch_bounds__(256)
void to_chunked(const float* __restrict__ in, ushort* __restrict__ outc,
                int H, int W, int Cchunks) {
    int P = W + 2, Q = H + 2;
    int plane_px = P * Q;
    int idx = blockIdx.x * 256 + threadIdx.x;
    if (idx >= plane_px) return;
    int py = idx / P, px = idx - py * P;
    int bc = blockIdx.y;
    int b = bc / Cchunks, cc = bc - b * Cchunks;
    ushort* dst = outc + ((size_t)bc * plane_px + idx) * 32;
    if (py == 0 || py == Q - 1 || px == 0 || px == P - 1) {
        for (int c = 0; c < 32; ++c) dst[c] = 0;
        return;
    }
    int y = py - 1, x = px - 1;
    const float* src = in + ((size_t)b * (Cchunks * 32) + cc * 32) * H * W
                          + (size_t)y * W + x;
    for (int c = 0; c < 32; ++c)
        dst[c] = f2b(src[(size_t)c * H * W]);
}

// Merged depth+guide conversion (256x256): planes 0-3 depth, 4-7 guide.
__global__ __launch_bounds__(256)
void to_chunked_hi(const float* __restrict__ depth, const float* __restrict__ guide,
                   ushort* __restrict__ outc) {
    const int P = 258;
    int plane_px = P * P;
    int idx = blockIdx.x * 256 + threadIdx.x;
    if (idx >= plane_px) return;
    int py = idx / P, px = idx - py * P;
    int pl = blockIdx.y;                 // 0..7
    const float* srcb = (pl < 4) ? depth : guide;
    int bc = pl & 3;
    int b = bc >> 1, cc = bc & 1;
    ushort* dst = outc + ((size_t)pl * plane_px + idx) * 32;
    if (py == 0 || py == P - 1 || px == 0 || px == P - 1) {
        for (int c = 0; c < 32; ++c) dst[c] = 0;
        return;
    }
    int y = py - 1, x = px - 1;
    const float* src = srcb + ((size_t)b * 64 + cc * 32) * HW2 + (size_t)y * 256 + x;
    for (int c = 0; c < 32; ++c)
        dst[c] = f2b(src[(size_t)c * HW2]);
}

// ---------------------------------------------------------------------------
// Zero 1-px borders of both conv-output regions in one dispatch.
// ---------------------------------------------------------------------------
__global__ __launch_bounds__(256)
void zero_border2(ushort* __restrict__ buf256, ushort* __restrict__ buf128) {
    int region = blockIdx.y;
    int H = region ? 128 : 256;
    int P = H + 2, Q = H + 2;
    ushort* buf = region ? buf128 : buf256;
    int nb = 2 * P + 2 * H;
    int idx = blockIdx.x * 256 + threadIdx.x;
    if (idx >= nb * 8) return;
    int pl = idx / nb, r = idx - pl * nb;
    int py, px;
    if (r < P)          { py = 0;     px = r; }
    else if (r < 2 * P) { py = Q - 1; px = r - P; }
    else { int k = r - 2 * P; py = 1 + (k >> 1); px = (k & 1) ? P - 1 : 0; }
    ushort* dst = buf + ((size_t)pl * P * Q + (size_t)py * P + px) * 32;
    for (int c = 0; c < 32; ++c) dst[c] = 0;
}

// ---------------------------------------------------------------------------
// LDS-free, barrier-free implicit-GEMM conv3x3 (pad=1), Cout=64.
// ---------------------------------------------------------------------------
template<int NCHUNK, int ROWS, bool RELU, bool HAS_SKIP, bool CONCAT2>
__global__ __launch_bounds__(256)
void conv3x3_reg(const ushort* __restrict__ inA, const ushort* __restrict__ inB,
                 const ushort* __restrict__ wt, const float* __restrict__ bias,
                 const ushort* __restrict__ skip, ushort* __restrict__ outc,
                 int H, int W) {
    const int P = W + 2;
    const size_t plane = (size_t)P * (H + 2) * 32;
    int tid = threadIdx.x;
    int wv = tid >> 6, lane = tid & 63, ml = lane & 15, q = lane >> 4;
    int x0 = blockIdx.x * 16;
    int rowsPerBlock = (blockDim.x >> 6) * ROWS;
    int yb = blockIdx.y * rowsPerBlock + wv * ROWS;
    int b = blockIdx.z;

    floatx4 acc[ROWS][4];
#pragma unroll
    for (int r = 0; r < ROWS; ++r)
#pragma unroll
        for (int n = 0; n < 4; ++n) acc[r][n] = (floatx4){0.f, 0.f, 0.f, 0.f};

    for (int cc = 0; cc < NCHUNK; ++cc) {
        const ushort* base;
        if (CONCAT2) {
            constexpr int HC = NCHUNK / 2;
            if (cc < HC) base = inA + ((size_t)(b * HC + cc)) * plane;
            else         base = inB + ((size_t)(b * HC + cc - HC)) * plane;
        } else {
            base = inA + ((size_t)(b * NCHUNK + cc)) * plane;
        }
        const ushort* wb = wt + (size_t)cc * 18432;
#pragma unroll
        for (int t = 0; t < 9; ++t) {
            int dy = t / 3, dx = t - 3 * dy;
            short8 afr[ROWS], bfr[4];
#pragma unroll
            for (int r = 0; r < ROWS; ++r)
                afr[r] = *(const short8*)&base[((size_t)(yb + r + dy) * P
                                               + (x0 + ml + dx)) * 32 + q * 8];
#pragma unroll
            for (int n = 0; n < 4; ++n)
                bfr[n] = *(const short8*)&wb[(size_t)(t * 64 + n * 16 + ml) * 32 + q * 8];
#pragma unroll
            for (int r = 0; r < ROWS; ++r)
#pragma unroll
                for (int n = 0; n < 4; ++n)
                    acc[r][n] = __builtin_amdgcn_mfma_f32_16x16x32_bf16(
                        afr[r], bfr[n], acc[r][n], 0, 0, 0);
        }
    }

#pragma unroll
    for (int r = 0; r < ROWS; ++r) {
        int y = yb + r;
#pragma unroll
        for (int n = 0; n < 4; ++n) {
            int ch = n * 16 + ml;
            int occ = ch >> 5, ocl = ch & 31;
            float bs = bias[ch];
            size_t pbase = ((size_t)(b * 2 + occ)) * plane + ((size_t)(y + 1) * P) * 32 + ocl;
#pragma unroll
            for (int e = 0; e < 4; ++e) {
                int x = x0 + q * 4 + e;
                float v = acc[r][n][e] + bs;
                if (RELU) v = fmaxf(v, 0.f);
                if (HAS_SKIP)
                    v += b2f(skip[((size_t)(b * 2 + occ)) * plane
                                  + ((size_t)(y + 1) * P + (x + 1)) * 32 + ocl]);
                outc[pbase + (size_t)(x + 1) * 32] = f2b(v);
            }
        }
    }
}

// ---------------------------------------------------------------------------
// Fused: wn3 (MFMA, N=1-of-16) + dk/gk MFMA branches + softmax + blend +
// tanh + L1. Wave owns 16 pixels; all GEMMs per-wave, no block barrier.
// ---------------------------------------------------------------------------
__global__ __launch_bounds__(256)
void kernels_fuse_mfma(const ushort* __restrict__ depth_c, const ushort* __restrict__ guide_c,
                       const ushort* __restrict__ bufB,
                       const ushort* __restrict__ wt3, const float* __restrict__ wn_b3,
                       const ushort* __restrict__ w1d, const float* __restrict__ b1d,
                       const ushort* __restrict__ w2d, const float* __restrict__ b2d,
                       const ushort* __restrict__ w1g, const float* __restrict__ b1g,
                       const ushort* __restrict__ w2g, const float* __restrict__ b2g,
                       const float* __restrict__ aff, float* __restrict__ fuse_out) {
    __shared__ __align__(16) ushort hid[2][4][16 * 72];
    __shared__ float wmv[4][16];

    int tid = threadIdx.x;
    int wv = tid >> 6, lane = tid & 63, ml = lane & 15, q = lane >> 4;
    int p0 = blockIdx.x * 64 + wv * 16;
    int b = p0 >> 16, rem0 = p0 & 65535;
    const size_t plane = (size_t)258 * 258 * 32;

    int rem = rem0 + ml;
    int y = rem >> 8, x = rem & 255;
    size_t poff = ((size_t)(y + 1) * 258 + (x + 1)) * 32;

    // ---- wmap (wn3) via MFMA: M=16 px, K=576 (18 chunks), col 0 valid ----
    floatx4 dwm = (floatx4){0.f, 0.f, 0.f, 0.f};
#pragma unroll
    for (int cc = 0; cc < 2; ++cc) {
        const ushort* basep = bufB + (size_t)(b * 2 + cc) * plane;
#pragma unroll
        for (int t = 0; t < 9; ++t) {
            int dy = t / 3, dx = t - 3 * dy;
            short8 a3 = *(const short8*)&basep[((size_t)(y + dy) * 258 + (x + dx)) * 32 + q * 8];
            short8 b3 = *(const short8*)&wt3[(size_t)((cc * 9 + t) * 512 + ml * 32 + q * 8)];
            dwm = __builtin_amdgcn_mfma_f32_16x16x32_bf16(a3, b3, dwm, 0, 0, 0);
        }
    }
    // col 0 (lanes ml==0) holds wmap for pixels q*4+e; broadcast via LDS
    if (ml == 0) {
#pragma unroll
        for (int e = 0; e < 4; ++e) wmv[wv][q * 4 + e] = dwm[e];
    }
    float wm = wmv[wv][ml] + wn_b3[0];   // same-wave LDS RAW: in-order DS, no barrier

    float sm[2][4];
    for (int br = 0; br < 2; ++br) {
        const ushort* src = br ? guide_c : depth_c;
        const ushort* w1  = br ? w1g : w1d;
        const float*  b1  = br ? b1g : b1d;
        const ushort* w2  = br ? w2g : w2d;
        const float*  b2  = br ? b2g : b2d;
        ushort* h = hid[br][wv];

        short8 afr[2];
#pragma unroll
        for (int kc = 0; kc < 2; ++kc)
            afr[kc] = *(const short8*)&src[(size_t)(b * 2 + kc) * plane + poff + q * 8];

        floatx4 acc[4];
#pragma unroll
        for (int nt = 0; nt < 4; ++nt) acc[nt] = (floatx4){0.f, 0.f, 0.f, 0.f};
#pragma unroll
        for (int nt = 0; nt < 4; ++nt)
#pragma unroll
            for (int kc = 0; kc < 2; ++kc) {
                short8 bfr = *(const short8*)&w1[(size_t)((nt * 16 + ml) * 64 + kc * 32 + q * 8)];
                acc[nt] = __builtin_amdgcn_mfma_f32_16x16x32_bf16(afr[kc], bfr, acc[nt], 0, 0, 0);
            }

        // bias + ReLU, transpose via LDS (same-wave round-trip, no barrier)
#pragma unroll
        for (int nt = 0; nt < 4; ++nt) {
            float bs = b1[nt * 16 + ml];
#pragma unroll
            for (int e = 0; e < 4; ++e) {
                float v = acc[nt][e] + bs;
                v = fmaxf(v, 0.f);
                h[(q * 4 + e) * 72 + nt * 16 + ml] = f2b(v);
            }
        }

        floatx4 d2 = (floatx4){0.f, 0.f, 0.f, 0.f};
#pragma unroll
        for (int kc = 0; kc < 2; ++kc) {
            short8 a2 = *(const short8*)&w2[(size_t)(ml * 64 + kc * 32 + q * 8)];
            short8 hf = *(const short8*)&h[ml * 72 + kc * 32 + q * 8];
            d2 = __builtin_amdgcn_mfma_f32_16x16x32_bf16(a2, hf, d2, 0, 0, 0);
        }

        float lg[4];
#pragma unroll
        for (int e = 0; e < 4; ++e) {
            int j = q * 4 + e;
            lg[e] = (j < 9) ? (d2[e] + b2[j]) : -1e30f;
        }
        float m = fmaxf(fmaxf(lg[0], lg[1]), fmaxf(lg[2], lg[3]));
        m = fmaxf(m, __shfl_xor(m, 16));
        m = fmaxf(m, __shfl_xor(m, 32));
        float s = 0.f;
#pragma unroll
        for (int e = 0; e < 4; ++e) { lg[e] = __expf(lg[e] - m); s += lg[e]; }
        s += __shfl_xor(s, 16);
        s += __shfl_xor(s, 32);
        float inv = 1.f / s;
#pragma unroll
        for (int e = 0; e < 4; ++e) sm[br][e] = lg[e] * inv;
    }

    float inv_av = 1.f / (aff[0] + 1e-8f);
    float f[4];
    float s = 0.f;
#pragma unroll
    for (int e = 0; e < 4; ++e) {
        float v = wm * sm[0][e] + (1.f - wm) * sm[1][e];
        v = tanhf(v) * inv_av;
        f[e] = v;
        s += fabsf(v);
    }
    s += __shfl_xor(s, 16);
    s += __shfl_xor(s, 32);
    float ksum = s + 1e-4f;
    if (ksum < 1.f) ksum = 1.f;
    float invk = 1.f / ksum;
#pragma unroll
    for (int e = 0; e < 4; ++e) {
        int j = q * 4 + e;
        if (j < 9)
            fuse_out[((size_t)b * 9 + j) * HW2 + rem0 + ml] = f[e] * invk;
    }
}

// ---------------------------------------------------------------------------
// Fused bilinear-upsample + 9-tap dilated gather (4x4 stencil on r2).
// ---------------------------------------------------------------------------
__global__ __launch_bounds__(256)
void fuse_apply_up(const float* __restrict__ fuse, const ushort* __restrict__ r2c,
                   float* __restrict__ out) {
    int p = blockIdx.x * 256 + threadIdx.x;
    int pl = blockIdx.y;
    int b = pl >> 1, cc = pl & 1;
    int y = p >> 8, x = p & 255;

    int my = y >> 1, mx = x >> 1;
    float wyA = (y & 1) ? 0.75f : 0.25f;  float wyB = 1.f - wyA;
    float wxA = (x & 1) ? 0.75f : 0.25f;  float wxB = 1.f - wxA;
    int R0y = my + ((y & 1) ? 0 : -1) - 1;
    int R0x = mx + ((x & 1) ? 0 : -1) - 1;

    const float* f = fuse + (size_t)b * 9 * HW2 + p;
    float coef[4][4];
#pragma unroll
    for (int k = 0; k < 4; ++k)
#pragma unroll
        for (int l = 0; l < 4; ++l) coef[k][l] = 0.f;

#pragma unroll
    for (int ty = 0; ty < 3; ++ty) {
        int yp = y + (ty - 1) * 2;
        if (yp < 0 || yp > 255) continue;
#pragma unroll
        for (int tx = 0; tx < 3; ++tx) {
            int xp = x + (tx - 1) * 2;
            if (xp < 0 || xp > 255) continue;
            float fv = f[(size_t)(ty * 3 + tx) * HW2];
            coef[ty][tx]         += fv * wyA * wxA;
            coef[ty][tx + 1]     += fv * wyA * wxB;
            coef[ty + 1][tx]     += fv * wyB * wxA;
            coef[ty + 1][tx + 1] += fv * wyB * wxB;
        }
    }

    const ushort* base = r2c + (size_t)pl * 130 * 130 * 32;
    float acc[32];
#pragma unroll
    for (int c = 0; c < 32; ++c) acc[c] = 0.f;
#pragma unroll
    for (int k = 0; k < 4; ++k) {
        int ry = R0y + k; ry = ry < 0 ? 0 : (ry > 127 ? 127 : ry);
#pragma unroll
        for (int l = 0; l < 4; ++l) {
            int rx = R0x + l; rx = rx < 0 ? 0 : (rx > 127 ? 127 : rx);
            float cf = coef[k][l];
            const ushort* u = base + ((size_t)(ry + 1) * 130 + (rx + 1)) * 32;
#pragma unroll
            for (int c = 0; c < 32; ++c) acc[c] = fmaf(cf, b2f(u[c]), acc[c]);
        }
    }
    float* ob = out + ((size_t)(b * 64 + cc * 32)) * HW2 + p;
#pragma unroll
    for (int c = 0; c < 32; ++c) ob[(size_t)c * HW2] = acc[c];
}

// ---------------------------------------------------------------------------
extern "C" void kernel_launch(void* const* d_in, const int* in_sizes, int n_in,
                              void* d_out, int out_size, void* d_ws, size_t ws_size,
                              hipStream_t stream) {
    const float* depth  = (const float*)d_in[0];
    const float* guide  = (const float*)d_in[1];
    const float* inputs = (const float*)d_in[2];
    const float* dk_w1  = (const float*)d_in[3];
    const float* dk_b1  = (const float*)d_in[4];
    const float* dk_w2  = (const float*)d_in[5];
    const float* dk_b2  = (const float*)d_in[6];
    const float* gk_w1  = (const float*)d_in[7];
    const float* gk_b1  = (const float*)d_in[8];
    const float* gk_w2  = (const float*)d_in[9];
    const float* gk_b2  = (const float*)d_in[10];
    const float* wn_w1  = (const float*)d_in[11];
    const float* wn_b1  = (const float*)d_in[12];
    const float* wn_w2  = (const float*)d_in[13];
    const float* wn_b2  = (const float*)d_in[14];
    const float* wn_w3  = (const float*)d_in[15];
    const float* wn_b3  = (const float*)d_in[16];
    const float* rb_w   = (const float*)d_in[17];
    const float* rb_b   = (const float*)d_in[18];
    const float* aff    = (const float*)d_in[19];
    float* out = (float*)d_out;

    // ---- workspace layout (float units) ----
    float* ws = (float*)d_ws;
    size_t off = 0;
    const size_t CH256 = 4260096;   // 4 planes * 258*258*32 ushorts / 2
    const size_t CH128 = 1081600;   // 4 planes * 130*130*32 ushorts / 2
    ushort* depth_c = (ushort*)(ws + off); off += CH256;
    ushort* guide_c = (ushort*)(ws + off); off += CH256;
    ushort* bufA    = (ushort*)(ws + off); off += CH256;
    ushort* bufB    = (ushort*)(ws + off); off += CH256;
    ushort* inp_c   = (ushort*)(ws + off); off += CH128;
    ushort* r0      = (ushort*)(ws + off); off += CH128;
    ushort* r1      = (ushort*)(ws + off); off += CH128;
    ushort* r2      = (ushort*)(ws + off); off += CH128;
    float* fuse     = ws + off; off += 1179648;
    ushort* wt_wn1  = (ushort*)(ws + off); off += 36864;
    ushort* wt_wn2  = (ushort*)(ws + off); off += 18432;
    ushort* wt_rb   = (ushort*)(ws + off); off += 73728;
    ushort* w1d_b   = (ushort*)(ws + off); off += 2048;
    ushort* w1g_b   = (ushort*)(ws + off); off += 2048;
    ushort* w2d_b   = (ushort*)(ws + off); off += 512;
    ushort* w2g_b   = (ushort*)(ws + off); off += 512;
    ushort* wt3_b   = (ushort*)(ws + off); off += 4608;   // 9216 bf16

    // ---- weight repack: 1 dispatch ----
    repack_all<<<dim3(288, 8), 256, 0, stream>>>(
        wn_w1, wn_w2, rb_w, dk_w1, gk_w1, dk_w2, gk_w2, wn_w3,
        wt_wn1, wt_wn2, wt_rb, w1d_b, w1g_b, w2d_b, w2g_b, wt3_b);

    // ---- activation layout conversion ----
    to_chunked_hi<<<dim3(261, 8), 256, 0, stream>>>(depth, guide, depth_c);
    to_chunked<<<dim3(67, 4), 256, 0, stream>>>(inputs, inp_c, 128, 128, 2);

    // ---- zero borders of conv-output buffers ----
    zero_border2<<<dim3(33, 2), 256, 0, stream>>>(bufA, r0);

    // ---- weight-map trunk ----
    conv3x3_reg<4, 4, true, false, true ><<<dim3(16, 16, 2), 256, 0, stream>>>(
        depth_c, guide_c, wt_wn1, wn_b1, nullptr, bufA, 256, 256);
    conv3x3_reg<2, 4, true, false, false><<<dim3(16, 16, 2), 256, 0, stream>>>(
        bufA, nullptr, wt_wn2, wn_b2, nullptr, bufB, 256, 256);

    // ---- wn3 (MFMA) + dk/gk branches + blend + tanh + normalize ----
    kernels_fuse_mfma<<<2048, 256, 0, stream>>>(depth_c, guide_c, bufB,
                                                wt3_b, wn_b3,
                                                w1d_b, dk_b1, w2d_b, dk_b2,
                                                w1g_b, gk_b1, w2g_b, gk_b2,
                                                aff, fuse);

    // ---- residual stack (128x128), 2 rows/wave ----
    conv3x3_reg<2, 2, true,  false, false><<<dim3(8, 16, 2), 256, 0, stream>>>(
        inp_c, nullptr, wt_rb + 0 * 36864, rb_b + 0 * 64, nullptr, r0, 128, 128);
    conv3x3_reg<2, 2, false, true,  false><<<dim3(8, 16, 2), 256, 0, stream>>>(
        r0, nullptr, wt_rb + 1 * 36864, rb_b + 1 * 64, inp_c, r1, 128, 128);
    conv3x3_reg<2, 2, true,  false, false><<<dim3(8, 16, 2), 256, 0, stream>>>(
        r1, nullptr, wt_rb + 2 * 36864, rb_b + 2 * 64, nullptr, r0, 128, 128);
    conv3x3_reg<2, 2, false, true,  false><<<dim3(8, 16, 2), 256, 0, stream>>>(
        r0, nullptr, wt_rb + 3 * 36864, rb_b + 3 * 64, r1, r2, 128, 128);

    // ---- fused upsample + 9-tap dilated gather ----
    fuse_apply_up<<<dim3(256, 4), 256, 0, stream>>>(fuse, r2, out);
}